// Round 1
// 227.109 us; speedup vs baseline: 1.0024x; 1.0024x over previous
//
#include <hip/hip_runtime.h>
#include <hip/hip_bf16.h>

#define RES 300
#define NPLANE (RES * RES)   // 90000
#define NC_A 48
#define APP_DIM 27
#define KDIM 144             // 3 * NC_A
#define KS 168               // prod LDS row stride in shorts (336 B, 16B-aligned)

#define PT_TILES 1407        // ceil(90000 / 64) p-tiles per plane
#define NPB2 (3 * PT_TILES)  // 4221 plane-transpose blocks

// bf16 (packed in uint halves) -> f32
__device__ __forceinline__ float bf_lo(unsigned int u) { return __uint_as_float(u << 16); }
__device__ __forceinline__ float bf_hi(unsigned int u) { return __uint_as_float(u & 0xffff0000u); }

// ---------------------------------------------------------------------------
// Unified prep kernel.
//   blocks [0,4221):    plane transpose (3,64,300,300) f32 -> Tp (3,90000,64)
//                       bf16 via LDS tile: dense 256B read segments per
//                       channel, fully dense 128B-row stores (no scatter).
//   blocks [4221,4236): line transpose -> TlP (3,300,64) packed bf16x2 (y,y+1)
//   block  4236:        pre-pack MFMA B-fragments of basis_W (bf16, 10 KB)
// ---------------------------------------------------------------------------
__global__ __launch_bounds__(256) void prep(
    const float* __restrict__ plane, const float* __restrict__ line,
    const float* __restrict__ W,
    unsigned int* __restrict__ TpUo, unsigned int* __restrict__ TlP,
    __hip_bfloat16* __restrict__ Wg) {
  __shared__ __align__(16) unsigned int lt[64 * 65];   // plane: stride-34 tile; line: 64x65
  const int blk = blockIdx.x;
  const int tid = threadIdx.x;

  if (blk < NPB2) {
    // ---- plane transpose, one 64p x 64c tile per block ----
    const int i  = blk / PT_TILES;
    const int t0 = blk - i * PT_TILES;
    const int p0 = t0 * 64;

    const int cb   = (tid >> 4) * 4;   // channel base (4 adjacent channels)
    const int poff = (tid & 15) * 4;   // p offset within tile
    const bool ok  = (p0 + poff) < NPLANE;

    // 4 passes: wave reads 4 channels x 256B dense segments per pass
    const float* src = plane + (size_t)(i * 64 + cb) * NPLANE + p0 + poff;
    float4 v0, v1, v2, v3;
    v0 = v1 = v2 = v3 = make_float4(0.f, 0.f, 0.f, 0.f);
    if (ok) {
      v0 = *(const float4*)(src);
      v1 = *(const float4*)(src + NPLANE);
      v2 = *(const float4*)(src + 2 * NPLANE);
      v3 = *(const float4*)(src + 3 * NPLANE);
    }
    // pack channel pairs (cb,cb+1) and (cb+2,cb+3), write LDS (stride 34 uints)
    const int col = (tid >> 4) * 2;
    const float* f0 = &v0.x; const float* f1 = &v1.x;
    const float* f2 = &v2.x; const float* f3 = &v3.x;
    #pragma unroll
    for (int j = 0; j < 4; ++j) {
      __hip_bfloat162 ha, hb;
      ha.x = __float2bfloat16(f0[j]);
      ha.y = __float2bfloat16(f1[j]);
      hb.x = __float2bfloat16(f2[j]);
      hb.y = __float2bfloat16(f3[j]);
      uint2 u;
      u.x = *(unsigned int*)&ha;
      u.y = *(unsigned int*)&hb;
      *(uint2*)&lt[(poff + j) * 34 + col] = u;
    }
    __syncthreads();
    // store: wave writes 8 full 128B rows per inst (fully dense)
    #pragma unroll
    for (int pass = 0; pass < 2; ++pass) {
      int p  = (tid >> 3) + pass * 32;
      int c4 = (tid & 7) * 4;
      if (p0 + p < NPLANE) {
        uint2 a = *(const uint2*)&lt[p * 34 + c4];
        uint2 b = *(const uint2*)&lt[p * 34 + c4 + 2];
        uint4 w; w.x = a.x; w.y = a.y; w.z = b.x; w.w = b.y;
        *(uint4*)&TpUo[((size_t)(i * NPLANE + p0 + p)) * 32 + c4] = w;
      }
    }
  } else if (blk < NPB2 + 15) {
    const int b  = blk - NPB2;
    const int i  = b / 5;
    const int y0 = (b % 5) * 64;
    const int yl = tid & 63;
    const int cq = tid >> 6;
    #pragma unroll
    for (int k = 0; k < 16; ++k) {
      int c = cq * 16 + k;
      int y = y0 + yl;
      float a = 0.f, bv = 0.f;
      if (y < RES) {
        const float* row = line + (i * 64 + c) * RES;
        a  = row[y];
        bv = row[min(y + 1, RES - 1)];
      }
      __hip_bfloat162 h;
      h.x = __float2bfloat16(a);
      h.y = __float2bfloat16(bv);
      lt[yl * 65 + c] = *(unsigned int*)&h;
    }
    __syncthreads();
    #pragma unroll
    for (int k = 0; k < 16; ++k) {
      int ylc = k * 4 + cq;
      int c   = tid & 63;
      int y   = y0 + ylc;
      if (y < RES) TlP[((size_t)i * RES + y) * 64 + c] = lt[ylc * 65 + c];
    }
  } else {
    // B-fragment pack: (((tile*5+kt)*64+lane)*8+j) = W[n][k], zero-padded
    for (int idx = tid; idx < 2 * 5 * 64 * 8; idx += 256) {
      int j    = idx & 7;
      int lane = (idx >> 3) & 63;
      int kt   = (idx >> 9) % 5;
      int tile = idx / (5 * 64 * 8);
      int n = tile * 16 + (lane & 15);
      int k = kt * 32 + (lane >> 4) * 8 + j;
      float v = (n < APP_DIM && k < KDIM) ? W[n * KDIM + k] : 0.f;
      Wg[idx] = __float2bfloat16(v);
    }
  }
}

// ---------------------------------------------------------------------------
// Main kernel: fused gather + blend + sigma + MFMA projection.
// 256 thr (4 waves), 64 samples/block. Channel-PAIR scheme: lane covers 2
// channels; half-waves process 2 samples per iteration. Phase 1 is software-
// pipelined: iteration it+1's 15 gather loads are issued before blending
// iteration it (full static unroll keeps both Gather sets in registers).
// launch_bounds(256,5): VGPR cap ~102 so the pipeline actually fits
// (the previous (256,6)/40-VGPR build serialized the gathers).
// LDS = 21504 (prod) + 4608 (cw) = 26112 B.
// ---------------------------------------------------------------------------
typedef __attribute__((ext_vector_type(8))) short short8;
typedef __attribute__((ext_vector_type(4))) float f32x4;

struct Gather {
  unsigned int u00[3], u01[3], u10[3], u11[3];
  uint2 ul[3];
  float w[3][5];
};

__device__ __forceinline__ void gather_it(
    const float* __restrict__ cp, const unsigned int* __restrict__ TpU,
    const unsigned int* __restrict__ TlP, int cl, int c2, Gather& g) {
  #pragma unroll
  for (int i = 0; i < 3; ++i) {
    float2 q0 = *(const float2*)&cp[i * 6];       // pack, w00
    float2 q1 = *(const float2*)&cp[i * 6 + 2];   // w01, w10
    float2 q2 = *(const float2*)&cp[i * 6 + 4];   // w11, lwy
    int pk   = __float_as_int(q0.x);
    int cell = pk & 0x7FFFF;
    int lidx = pk >> 19;
    int bidx = cell * 32 + cl;                    // uint index into TpU
    g.u00[i] = TpU[bidx];
    g.u01[i] = TpU[bidx + 32];
    g.u10[i] = TpU[bidx + RES * 32];
    g.u11[i] = TpU[bidx + RES * 32 + 32];
    g.ul[i]  = *(const uint2*)&TlP[(lidx << 6) + c2];
    g.w[i][0] = q0.y; g.w[i][1] = q1.x; g.w[i][2] = q1.y;
    g.w[i][3] = q2.x; g.w[i][4] = q2.y;
  }
}

__global__ __launch_bounds__(256, 5) void tensorf_main(
    const float* __restrict__ xyz, const unsigned int* __restrict__ TpU,
    const unsigned int* __restrict__ TlP, const __hip_bfloat16* __restrict__ Wg,
    float* __restrict__ out, int n_total) {
  __shared__ __hip_bfloat16 prod[64 * KS];
  __shared__ float cw[64 * 18];

  const int tid  = threadIdx.x;
  const int lane = tid & 63;
  const int wave = tid >> 6;
  const int n0   = blockIdx.x * 64;

  // zero prod k-pad [144,168)
  for (int j = tid; j < 64 * 12; j += 256) {
    int s = j / 12, kk = (j % 12) * 2;
    *(unsigned int*)&prod[s * KS + KDIM + kk] = 0u;
  }

  // Phase 0: per-sample precompute — packed cell/line index + 4 bilinear
  // weights + line weight. 6 floats per plane per sample.
  if (tid < 64) {
    int n = min(n0 + tid, n_total - 1);
    float crd[3] = {xyz[3 * n], xyz[3 * n + 1], xyz[3 * n + 2]};
    const int m0s[3] = {0, 0, 1}, m1s[3] = {1, 2, 2}, vms[3] = {2, 1, 0};
    float* c = &cw[tid * 18];
    #pragma unroll
    for (int i = 0; i < 3; ++i) {
      float ix = fminf(fmaxf((crd[m0s[i]] + 1.f) * 149.5f, 0.f), 299.f);
      float iy = fminf(fmaxf((crd[m1s[i]] + 1.f) * 149.5f, 0.f), 299.f);
      float ly = fminf(fmaxf((crd[vms[i]] + 1.f) * 149.5f, 0.f), 299.f);
      float x0f = fminf(floorf(ix), 298.f);
      float y0f = fminf(floorf(iy), 298.f);
      float l0f = fminf(floorf(ly), 298.f);
      float wx = ix - x0f, wy = iy - y0f, lwy = ly - l0f;
      int cell = i * NPLANE + (int)y0f * RES + (int)x0f;   // < 2^19
      int lidx = i * RES + (int)l0f;                       // < 2^10
      c[i * 6 + 0] = __int_as_float(cell | (lidx << 19));
      c[i * 6 + 1] = (1.f - wx) * (1.f - wy);
      c[i * 6 + 2] = wx * (1.f - wy);
      c[i * 6 + 3] = (1.f - wx) * wy;
      c[i * 6 + 4] = wx * wy;
      c[i * 6 + 5] = lwy;
    }
  }
  __syncthreads();

  // Phase 1: software-pipelined gather + blend
  const int cl   = lane & 31;
  const int half = lane >> 5;
  const int c2   = cl * 2;

  Gather cur, nxt;
  gather_it(&cw[(wave * 16 + half) * 18], TpU, TlP, cl, c2, cur);
  #pragma unroll
  for (int it = 0; it < 8; ++it) {
    const int s = wave * 16 + it * 2 + half;
    if (it < 7)
      gather_it(&cw[(s + 2) * 18], TpU, TlP, cl, c2, nxt);

    float dsum = 0.f;
    #pragma unroll
    for (int i = 0; i < 3; ++i) {
      float pf_l = cur.w[i][0] * bf_lo(cur.u00[i]) + cur.w[i][1] * bf_lo(cur.u01[i]) +
                   cur.w[i][2] * bf_lo(cur.u10[i]) + cur.w[i][3] * bf_lo(cur.u11[i]);
      float pf_h = cur.w[i][0] * bf_hi(cur.u00[i]) + cur.w[i][1] * bf_hi(cur.u01[i]) +
                   cur.w[i][2] * bf_hi(cur.u10[i]) + cur.w[i][3] * bf_hi(cur.u11[i]);
      float lal = bf_lo(cur.ul[i].x), lbl = bf_hi(cur.ul[i].x);
      float lah = bf_lo(cur.ul[i].y), lbh = bf_hi(cur.ul[i].y);
      float lf_l = lal + cur.w[i][4] * (lbl - lal);
      float lf_h = lah + cur.w[i][4] * (lbh - lah);
      float prl = pf_l * lf_l, prh = pf_h * lf_h;
      if (cl < 24) {    // app channel pairs 0..46
        __hip_bfloat162 h;
        h.x = __float2bfloat16(prl);
        h.y = __float2bfloat16(prh);
        *(unsigned int*)&prod[s * KS + i * NC_A + c2] = *(unsigned int*)&h;
      } else {          // density channel pairs 48..62
        dsum += prl + prh;
      }
    }
    // butterfly within the 8-lane density group (aligned: 24..31 / 56..63)
    dsum += __shfl_xor(dsum, 1);
    dsum += __shfl_xor(dsum, 2);
    dsum += __shfl_xor(dsum, 4);
    int n = n0 + s;
    if (cl == 24 && n < n_total) out[n] = dsum;
    if (it < 7) cur = nxt;
  }
  __syncthreads();

  // Phase 2: app = prod(64x144) @ W^T via mfma 16x16x32 bf16, B from Wg
  const int srow = lane & 15, quad = lane >> 4;
  f32x4 acc0 = {0.f, 0.f, 0.f, 0.f}, acc1 = {0.f, 0.f, 0.f, 0.f};
  const short* prodS = (const short*)prod;
  const short* WgS   = (const short*)Wg;
  const int arow = (wave * 16 + srow) * KS;
  #pragma unroll
  for (int kt = 0; kt < 5; ++kt) {
    short8 a  = *(const short8*)&prodS[arow + kt * 32 + quad * 8];
    short8 b0 = *(const short8*)&WgS[(kt * 64 + lane) * 8];
    short8 b1 = *(const short8*)&WgS[((5 + kt) * 64 + lane) * 8];
    acc0 = __builtin_amdgcn_mfma_f32_16x16x32_bf16(a, b0, acc0, 0, 0, 0);
    acc1 = __builtin_amdgcn_mfma_f32_16x16x32_bf16(a, b1, acc1, 0, 0, 0);
  }
  // C/D layout: col(d) = lane&15, row(sample) = quad*4 + reg
  float* outApp = out + n_total;
  #pragma unroll
  for (int r = 0; r < 4; ++r) {
    int n = n0 + wave * 16 + quad * 4 + r;
    if (n < n_total) {
      outApp[(size_t)n * APP_DIM + srow] = acc0[r];
      if (srow < APP_DIM - 16)
        outApp[(size_t)n * APP_DIM + 16 + srow] = acc1[r];
    }
  }
}

// ---------------------------------------------------------------------------
extern "C" void kernel_launch(void* const* d_in, const int* in_sizes, int n_in,
                              void* d_out, int out_size, void* d_ws, size_t ws_size,
                              hipStream_t stream) {
  const float* xyz   = (const float*)d_in[0];
  const float* plane = (const float*)d_in[1];
  const float* line  = (const float*)d_in[2];
  const float* W     = (const float*)d_in[3];
  float* out = (float*)d_out;
  const int N = in_sizes[0] / 3;

  char* ws = (char*)d_ws;
  __hip_bfloat16* Tp  = (__hip_bfloat16*)ws;                        // 34,560,000 B
  unsigned int*   TlP = (unsigned int*)(ws + 34560000);             //    230,400 B
  __hip_bfloat16* Wg  = (__hip_bfloat16*)(ws + 34560000 + 230400);  //     10,240 B

  prep<<<NPB2 + 16, 256, 0, stream>>>(plane, line, W, (unsigned int*)Tp, TlP, Wg);
  tensorf_main<<<(N + 63) / 64, 256, 0, stream>>>(
      xyz, (const unsigned int*)Tp, TlP, Wg, out, N);
}

// Round 3
// 224.979 us; speedup vs baseline: 1.0118x; 1.0095x over previous
//
#include <hip/hip_runtime.h>
#include <hip/hip_bf16.h>

#define RES 300
#define NPLANE (RES * RES)   // 90000
#define NC_A 48
#define APP_DIM 27
#define KDIM 144             // 3 * NC_A
#define KS 168               // prod LDS row stride in shorts (336 B, 16B-aligned)

#define PT_TILES 1407        // ceil(90000 / 64) p-tiles per plane
#define NPB2 (3 * PT_TILES)  // 4221 plane-transpose blocks

// bf16 (packed in uint halves) -> f32
__device__ __forceinline__ float bf_lo(unsigned int u) { return __uint_as_float(u << 16); }
__device__ __forceinline__ float bf_hi(unsigned int u) { return __uint_as_float(u & 0xffff0000u); }

// ---------------------------------------------------------------------------
// Unified prep kernel (unchanged from R1, which passed — dense 256B reads,
// dense 1KB row stores via LDS tile).
// ---------------------------------------------------------------------------
__global__ __launch_bounds__(256) void prep(
    const float* __restrict__ plane, const float* __restrict__ line,
    const float* __restrict__ W,
    unsigned int* __restrict__ TpUo, unsigned int* __restrict__ TlP,
    __hip_bfloat16* __restrict__ Wg) {
  __shared__ __align__(16) unsigned int lt[64 * 65];
  const int blk = blockIdx.x;
  const int tid = threadIdx.x;

  if (blk < NPB2) {
    const int i  = blk / PT_TILES;
    const int t0 = blk - i * PT_TILES;
    const int p0 = t0 * 64;

    const int cb   = (tid >> 4) * 4;
    const int poff = (tid & 15) * 4;
    const bool ok  = (p0 + poff) < NPLANE;

    const float* src = plane + (size_t)(i * 64 + cb) * NPLANE + p0 + poff;
    float4 v0, v1, v2, v3;
    v0 = v1 = v2 = v3 = make_float4(0.f, 0.f, 0.f, 0.f);
    if (ok) {
      v0 = *(const float4*)(src);
      v1 = *(const float4*)(src + NPLANE);
      v2 = *(const float4*)(src + 2 * NPLANE);
      v3 = *(const float4*)(src + 3 * NPLANE);
    }
    const int col = (tid >> 4) * 2;
    const float* f0 = &v0.x; const float* f1 = &v1.x;
    const float* f2 = &v2.x; const float* f3 = &v3.x;
    #pragma unroll
    for (int j = 0; j < 4; ++j) {
      __hip_bfloat162 ha, hb;
      ha.x = __float2bfloat16(f0[j]);
      ha.y = __float2bfloat16(f1[j]);
      hb.x = __float2bfloat16(f2[j]);
      hb.y = __float2bfloat16(f3[j]);
      uint2 u;
      u.x = *(unsigned int*)&ha;
      u.y = *(unsigned int*)&hb;
      *(uint2*)&lt[(poff + j) * 34 + col] = u;
    }
    __syncthreads();
    #pragma unroll
    for (int pass = 0; pass < 2; ++pass) {
      int p  = (tid >> 3) + pass * 32;
      int c4 = (tid & 7) * 4;
      if (p0 + p < NPLANE) {
        uint2 a = *(const uint2*)&lt[p * 34 + c4];
        uint2 b = *(const uint2*)&lt[p * 34 + c4 + 2];
        uint4 w; w.x = a.x; w.y = a.y; w.z = b.x; w.w = b.y;
        *(uint4*)&TpUo[((size_t)(i * NPLANE + p0 + p)) * 32 + c4] = w;
      }
    }
  } else if (blk < NPB2 + 15) {
    const int b  = blk - NPB2;
    const int i  = b / 5;
    const int y0 = (b % 5) * 64;
    const int yl = tid & 63;
    const int cq = tid >> 6;
    #pragma unroll
    for (int k = 0; k < 16; ++k) {
      int c = cq * 16 + k;
      int y = y0 + yl;
      float a = 0.f, bv = 0.f;
      if (y < RES) {
        const float* row = line + (i * 64 + c) * RES;
        a  = row[y];
        bv = row[min(y + 1, RES - 1)];
      }
      __hip_bfloat162 h;
      h.x = __float2bfloat16(a);
      h.y = __float2bfloat16(bv);
      lt[yl * 65 + c] = *(unsigned int*)&h;
    }
    __syncthreads();
    #pragma unroll
    for (int k = 0; k < 16; ++k) {
      int ylc = k * 4 + cq;
      int c   = tid & 63;
      int y   = y0 + ylc;
      if (y < RES) TlP[((size_t)i * RES + y) * 64 + c] = lt[ylc * 65 + c];
    }
  } else {
    for (int idx = tid; idx < 2 * 5 * 64 * 8; idx += 256) {
      int j    = idx & 7;
      int lane = (idx >> 3) & 63;
      int kt   = (idx >> 9) % 5;
      int tile = idx / (5 * 64 * 8);
      int n = tile * 16 + (lane & 15);
      int k = kt * 32 + (lane >> 4) * 8 + j;
      float v = (n < APP_DIM && k < KDIM) ? W[n * KDIM + k] : 0.f;
      Wg[idx] = __float2bfloat16(v);
    }
  }
}

// ---------------------------------------------------------------------------
// Main kernel: fused gather + blend + sigma + MFMA projection.
// Channel-QUAD scheme: lane&15 = channel quad (channels 4cq..4cq+3 via
// uint2 corner loads + uint4 line load), lane>>4 = sample slot -> 4 samples
// per wave-iteration, 4 phase-1 iterations (vs 8 in the pair scheme).
// Everything else (phase 0, stores, unroll policy) kept EXACTLY as the
// passing R0/R1 kernel — single-delta bisect after R2's failure.
// LDS = 21504 (prod) + 4608 (cw) = 26112 B.
// ---------------------------------------------------------------------------
typedef __attribute__((ext_vector_type(8))) short short8;
typedef __attribute__((ext_vector_type(4))) float f32x4;

__global__ __launch_bounds__(256, 5) void tensorf_main(
    const float* __restrict__ xyz, const unsigned int* __restrict__ TpU,
    const unsigned int* __restrict__ TlP, const __hip_bfloat16* __restrict__ Wg,
    float* __restrict__ out, int n_total) {
  __shared__ __hip_bfloat16 prod[64 * KS];
  __shared__ float cw[64 * 18];

  const int tid  = threadIdx.x;
  const int lane = tid & 63;
  const int wave = tid >> 6;
  const int n0   = blockIdx.x * 64;

  // zero prod k-pad [144,168)
  for (int j = tid; j < 64 * 12; j += 256) {
    int s = j / 12, kk = (j % 12) * 2;
    *(unsigned int*)&prod[s * KS + KDIM + kk] = 0u;
  }

  // Phase 0: per-sample precompute — EXACT R0 form (tid<64, unrolled planes).
  if (tid < 64) {
    int n = min(n0 + tid, n_total - 1);
    float crd[3] = {xyz[3 * n], xyz[3 * n + 1], xyz[3 * n + 2]};
    const int m0s[3] = {0, 0, 1}, m1s[3] = {1, 2, 2}, vms[3] = {2, 1, 0};
    float* c = &cw[tid * 18];
    #pragma unroll
    for (int i = 0; i < 3; ++i) {
      float ix = fminf(fmaxf((crd[m0s[i]] + 1.f) * 149.5f, 0.f), 299.f);
      float iy = fminf(fmaxf((crd[m1s[i]] + 1.f) * 149.5f, 0.f), 299.f);
      float ly = fminf(fmaxf((crd[vms[i]] + 1.f) * 149.5f, 0.f), 299.f);
      float x0f = fminf(floorf(ix), 298.f);
      float y0f = fminf(floorf(iy), 298.f);
      float l0f = fminf(floorf(ly), 298.f);
      float wx = ix - x0f, wy = iy - y0f, lwy = ly - l0f;
      int cell = i * NPLANE + (int)y0f * RES + (int)x0f;   // < 2^19
      int lidx = i * RES + (int)l0f;                       // < 2^10
      c[i * 6 + 0] = __int_as_float(cell | (lidx << 19));
      c[i * 6 + 1] = (1.f - wx) * (1.f - wy);
      c[i * 6 + 2] = wx * (1.f - wy);
      c[i * 6 + 3] = (1.f - wx) * wy;
      c[i * 6 + 4] = wx * wy;
      c[i * 6 + 5] = lwy;
    }
  }
  __syncthreads();

  // Phase 1: 4 iterations, 4 samples/wave-iter, 4 channels/lane
  const int cq = lane & 15;     // channel quad -> channels 4cq..4cq+3
  const int sq = lane >> 4;     // sample slot within iteration group
  const int c4 = cq * 4;

  #pragma unroll 2
  for (int it = 0; it < 4; ++it) {
    const int s = wave * 16 + it * 4 + sq;
    const float* cp = &cw[s * 18];

    // batched load phase: issue all 15 VMEM ops (36 dwords) before any use
    uint2 u00[3], u01[3], u10[3], u11[3];
    uint4 ul[3];
    float wgt[3][5];
    #pragma unroll
    for (int i = 0; i < 3; ++i) {
      float2 q0 = *(const float2*)&cp[i * 6];       // pack, w00
      float2 q1 = *(const float2*)&cp[i * 6 + 2];   // w01, w10
      float2 q2 = *(const float2*)&cp[i * 6 + 4];   // w11, lwy
      int pk   = __float_as_int(q0.x);
      int cell = pk & 0x7FFFF;
      int lidx = pk >> 19;
      int bidx = cell * 32 + cq * 2;                // uint index into TpU
      u00[i] = *(const uint2*)&TpU[bidx];
      u01[i] = *(const uint2*)&TpU[bidx + 32];
      u10[i] = *(const uint2*)&TpU[bidx + RES * 32];
      u11[i] = *(const uint2*)&TpU[bidx + RES * 32 + 32];
      ul[i]  = *(const uint4*)&TlP[(lidx << 6) + c4];
      wgt[i][0] = q0.y; wgt[i][1] = q1.x; wgt[i][2] = q1.y;
      wgt[i][3] = q2.x; wgt[i][4] = q2.y;
    }

    // blend phase
    float dsum = 0.f;
    #pragma unroll
    for (int i = 0; i < 3; ++i) {
      float w00 = wgt[i][0], w01 = wgt[i][1], w10 = wgt[i][2];
      float w11 = wgt[i][3], lw = wgt[i][4];
      // dword 0: channels 4cq, 4cq+1
      {
        float pf_l = w00 * bf_lo(u00[i].x) + w01 * bf_lo(u01[i].x) +
                     w10 * bf_lo(u10[i].x) + w11 * bf_lo(u11[i].x);
        float pf_h = w00 * bf_hi(u00[i].x) + w01 * bf_hi(u01[i].x) +
                     w10 * bf_hi(u10[i].x) + w11 * bf_hi(u11[i].x);
        float lal = bf_lo(ul[i].x), lbl = bf_hi(ul[i].x);
        float lah = bf_lo(ul[i].y), lbh = bf_hi(ul[i].y);
        float lf_l = lal + lw * (lbl - lal);
        float lf_h = lah + lw * (lbh - lah);
        float prl = pf_l * lf_l, prh = pf_h * lf_h;
        if (cq < 12) {
          __hip_bfloat162 h;
          h.x = __float2bfloat16(prl);
          h.y = __float2bfloat16(prh);
          *(unsigned int*)&prod[s * KS + i * NC_A + c4] = *(unsigned int*)&h;
        } else {
          dsum += prl + prh;
        }
      }
      // dword 1: channels 4cq+2, 4cq+3
      {
        float pf_l = w00 * bf_lo(u00[i].y) + w01 * bf_lo(u01[i].y) +
                     w10 * bf_lo(u10[i].y) + w11 * bf_lo(u11[i].y);
        float pf_h = w00 * bf_hi(u00[i].y) + w01 * bf_hi(u01[i].y) +
                     w10 * bf_hi(u10[i].y) + w11 * bf_hi(u11[i].y);
        float lal = bf_lo(ul[i].z), lbl = bf_hi(ul[i].z);
        float lah = bf_lo(ul[i].w), lbh = bf_hi(ul[i].w);
        float lf_l = lal + lw * (lbl - lal);
        float lf_h = lah + lw * (lbh - lah);
        float prl = pf_l * lf_l, prh = pf_h * lf_h;
        if (cq < 12) {
          __hip_bfloat162 h;
          h.x = __float2bfloat16(prl);
          h.y = __float2bfloat16(prh);
          *(unsigned int*)&prod[s * KS + i * NC_A + c4 + 2] = *(unsigned int*)&h;
        } else {
          dsum += prl + prh;
        }
      }
    }
    // density reduce across channel-quads 12..15 (4-aligned lane groups)
    dsum += __shfl_xor(dsum, 1);
    dsum += __shfl_xor(dsum, 2);
    int n = n0 + s;
    if (cq == 12 && n < n_total) out[n] = dsum;
  }
  __syncthreads();

  // Phase 2: app = prod(64x144) @ W^T via mfma 16x16x32 bf16, B from Wg
  const int srow = lane & 15, quad = lane >> 4;
  f32x4 acc0 = {0.f, 0.f, 0.f, 0.f}, acc1 = {0.f, 0.f, 0.f, 0.f};
  const short* prodS = (const short*)prod;
  const short* WgS   = (const short*)Wg;
  const int arow = (wave * 16 + srow) * KS;
  #pragma unroll
  for (int kt = 0; kt < 5; ++kt) {
    short8 a  = *(const short8*)&prodS[arow + kt * 32 + quad * 8];
    short8 b0 = *(const short8*)&WgS[(kt * 64 + lane) * 8];
    short8 b1 = *(const short8*)&WgS[((5 + kt) * 64 + lane) * 8];
    acc0 = __builtin_amdgcn_mfma_f32_16x16x32_bf16(a, b0, acc0, 0, 0, 0);
    acc1 = __builtin_amdgcn_mfma_f32_16x16x32_bf16(a, b1, acc1, 0, 0, 0);
  }
  // C/D layout: col(d) = lane&15, row(sample) = quad*4 + reg
  float* outApp = out + n_total;
  #pragma unroll
  for (int r = 0; r < 4; ++r) {
    int n = n0 + wave * 16 + quad * 4 + r;
    if (n < n_total) {
      outApp[(size_t)n * APP_DIM + srow] = acc0[r];
      if (srow < APP_DIM - 16)
        outApp[(size_t)n * APP_DIM + 16 + srow] = acc1[r];
    }
  }
}

// ---------------------------------------------------------------------------
extern "C" void kernel_launch(void* const* d_in, const int* in_sizes, int n_in,
                              void* d_out, int out_size, void* d_ws, size_t ws_size,
                              hipStream_t stream) {
  const float* xyz   = (const float*)d_in[0];
  const float* plane = (const float*)d_in[1];
  const float* line  = (const float*)d_in[2];
  const float* W     = (const float*)d_in[3];
  float* out = (float*)d_out;
  const int N = in_sizes[0] / 3;

  char* ws = (char*)d_ws;
  __hip_bfloat16* Tp  = (__hip_bfloat16*)ws;                        // 34,560,000 B
  unsigned int*   TlP = (unsigned int*)(ws + 34560000);             //    230,400 B
  __hip_bfloat16* Wg  = (__hip_bfloat16*)(ws + 34560000 + 230400);  //     10,240 B

  prep<<<NPB2 + 16, 256, 0, stream>>>(plane, line, W, (unsigned int*)Tp, TlP, Wg);
  tensorf_main<<<(N + 63) / 64, 256, 0, stream>>>(
      xyz, (const unsigned int*)Tp, TlP, Wg, out, N);
}